// Round 10
// baseline (287.978 us; speedup 1.0000x reference)
//
#include <hip/hip_runtime.h>
#include <hip/hip_bf16.h>

#define HIDC 64
#define NEG_SLOPE 0.2f
#define SCAN_G 128     // blocks in the two-phase scan

typedef __hip_bfloat16 bf16;
typedef short bf16x8 __attribute__((ext_vector_type(8)));
typedef float floatx4 __attribute__((ext_vector_type(4)));

static __device__ __forceinline__ float b2f(bf16 v) { return __bfloat162float(v); }

static __device__ __forceinline__ unsigned short f2us(float f) {
  bf16 b = __float2bfloat16(f);
  union { bf16 b; unsigned short u; } c;
  c.b = b;
  return c.u;
}

// dtype-specialized loads
template <bool FF>
static __device__ __forceinline__ float ld(const void* __restrict__ p, size_t i) {
  return FF ? ((const float*)p)[i] : b2f(((const bf16*)p)[i]);
}
static __device__ __forceinline__ float ldr(const void* __restrict__ p, size_t i,
                                            bool ff) {
  return ff ? ((const float*)p)[i] : b2f(((const bf16*)p)[i]);
}
template <bool I64>
static __device__ __forceinline__ int ldi(const int* __restrict__ p, long long i) {
  return I64 ? (int)((const long long*)p)[i] : p[i];
}
static __device__ __forceinline__ int clampN(int v, int N) {
  return ((unsigned)v < (unsigned)N) ? v : 0;
}

// Per-wave local dtype detection (1 load + ballot; wave-uniform result).
static __device__ __forceinline__ bool det_f32(const unsigned* __restrict__ hw) {
  unsigned w = hw[threadIdx.x & 31];
  int ex = (w >> 7) & 0xFF;
  unsigned long long b = __ballot(ex >= 99 && ex <= 135);
  return __popcll(b) < 32;  // true => fp32 inputs
}
static __device__ __forceinline__ bool det_i64(const int* __restrict__ ei) {
  int v = ei[2 * (threadIdx.x & 31) + 1];
  return __ballot(v != 0) == 0ULL;  // true => int64 layout
}

// wave-level inclusive scan (64 lanes)
static __device__ __forceinline__ int wave_iscan(int v, int lane) {
#pragma unroll
  for (int off = 1; off < 64; off <<= 1) {
    int u = __shfl_up(v, off);
    if (lane >= off) v += u;
  }
  return v;
}

// ---------------- MFMA x-GEMM + logits + in-degree histogram ----------------
// Block = 64 nodes x 256 cols. LDS tiles declared in the WRAPPER (4x-inlined
// template would otherwise get 4 copies -> 160 KB/block, the round-8 bug).
template <bool FF, bool I64>
static __device__ __forceinline__ void xh_body(
    const void* __restrict__ h, const void* __restrict__ W,
    const void* __restrict__ att_src, const void* __restrict__ att_dst,
    const int* __restrict__ ei, bf16* __restrict__ x,
    float* __restrict__ a_src, float* __restrict__ a_dst,
    int* __restrict__ cnt, int N, int E,
    unsigned short* __restrict__ hls, unsigned short* __restrict__ wls) {
  for (long long e = (long long)blockIdx.x * 256 + threadIdx.x; e < E;
       e += (long long)gridDim.x * 256) {
    int dst = clampN(ldi<I64>(ei, (long long)E + e), N);
    atomicAdd(&cnt[dst], 1);
  }
  const int t = threadIdx.x;
  const long long n0 = (long long)blockIdx.x * 64;
  {  // stage W^T: thread t = col c; global reads coalesced per k-row
    const int c = t;
#pragma unroll
    for (int q = 0; q < 8; q++) {
      unsigned short u[8];
#pragma unroll
      for (int j = 0; j < 8; j++) {
        int k = q * 8 + j;
        u[j] = FF ? f2us(((const float*)W)[(size_t)k * 256 + c])
                  : ((const unsigned short*)W)[(size_t)k * 256 + c];
      }
      int4 v = make_int4((int)(u[0] | ((unsigned)u[1] << 16)),
                         (int)(u[2] | ((unsigned)u[3] << 16)),
                         (int)(u[4] | ((unsigned)u[5] << 16)),
                         (int)(u[6] | ((unsigned)u[7] << 16)));
      *(int4*)&wls[c * 64 + (q ^ (c & 7)) * 8] = v;
    }
  }
  {  // stage h tile: 64 rows x 8 chunks
    const int row = t >> 2;
    const long long n = n0 + row;
#pragma unroll
    for (int dq = 0; dq < 2; dq++) {
      int q = (t & 3) * 2 + dq;
      int4 v;
      if (n < N) {
        if (FF) {
          const float4* hp = (const float4*)h + n * 16 + q * 2;
          float4 f0 = hp[0], f1 = hp[1];
          v = make_int4((int)(f2us(f0.x) | ((unsigned)f2us(f0.y) << 16)),
                        (int)(f2us(f0.z) | ((unsigned)f2us(f0.w) << 16)),
                        (int)(f2us(f1.x) | ((unsigned)f2us(f1.y) << 16)),
                        (int)(f2us(f1.z) | ((unsigned)f2us(f1.w) << 16)));
        } else {
          v = *((const int4*)((const unsigned short*)h + n * 64 + q * 8));
        }
      } else {
        v = make_int4(0, 0, 0, 0);
      }
      *(int4*)&hls[row * 64 + (q ^ (row & 7)) * 8] = v;
    }
  }
  __syncthreads();
  const int w = t >> 6;
  const int lane = t & 63;
  const int lm = lane & 15, lq = lane >> 4;
  bf16x8 af[4][2];
#pragma unroll
  for (int nt = 0; nt < 4; nt++)
#pragma unroll
    for (int ks = 0; ks < 2; ks++) {
      int m = nt * 16 + lm;
      int q = ks * 4 + lq;
      af[nt][ks] = *(const bf16x8*)&hls[m * 64 + (q ^ (m & 7)) * 8];
    }
  floatx4 acc[4][4];
#pragma unroll
  for (int nt = 0; nt < 4; nt++)
#pragma unroll
    for (int ct = 0; ct < 4; ct++) acc[nt][ct] = (floatx4){0.f, 0.f, 0.f, 0.f};
#pragma unroll
  for (int ct = 0; ct < 4; ct++) {
    int c = w * 64 + ct * 16 + lm;
    bf16x8 b0 = *(const bf16x8*)&wls[c * 64 + ((lq) ^ (c & 7)) * 8];
    bf16x8 b1 = *(const bf16x8*)&wls[c * 64 + ((4 + lq) ^ (c & 7)) * 8];
#pragma unroll
    for (int nt = 0; nt < 4; nt++) {
      acc[nt][ct] = __builtin_amdgcn_mfma_f32_16x16x32_bf16(af[nt][0], b0,
                                                            acc[nt][ct], 0, 0, 0);
      acc[nt][ct] = __builtin_amdgcn_mfma_f32_16x16x32_bf16(af[nt][1], b1,
                                                            acc[nt][ct], 0, 0, 0);
    }
  }
  float as_c[4], ad_c[4];
#pragma unroll
  for (int ct = 0; ct < 4; ct++) {
    as_c[ct] = ld<FF>(att_src, w * 64 + ct * 16 + lm);
    ad_c[ct] = ld<FF>(att_dst, w * 64 + ct * 16 + lm);
  }
#pragma unroll
  for (int nt = 0; nt < 4; nt++) {
    float ps[4] = {0.f, 0.f, 0.f, 0.f}, pd[4] = {0.f, 0.f, 0.f, 0.f};
#pragma unroll
    for (int ct = 0; ct < 4; ct++) {
#pragma unroll
      for (int r = 0; r < 4; r++) {
        ps[r] += acc[nt][ct][r] * as_c[ct];
        pd[r] += acc[nt][ct][r] * ad_c[ct];
      }
    }
    long long nb = n0 + nt * 16 + lq * 4;
#pragma unroll
    for (int r = 0; r < 4; r++) {
      long long n = nb + r;
      if (n < N) {
#pragma unroll
        for (int ct = 0; ct < 4; ct++)
          x[n * 256 + w * 64 + ct * 16 + lm] = __float2bfloat16(acc[nt][ct][r]);
      }
    }
#pragma unroll
    for (int mask = 1; mask < 16; mask <<= 1) {
#pragma unroll
      for (int r = 0; r < 4; r++) {
        ps[r] += __shfl_xor(ps[r], mask);
        pd[r] += __shfl_xor(pd[r], mask);
      }
    }
    if (lm == 0) {
#pragma unroll
      for (int r = 0; r < 4; r++) {
        long long n = nb + r;
        if (n < N) {
          a_src[n * 4 + w] = ps[r];
          a_dst[n * 4 + w] = pd[r];
        }
      }
    }
  }
}

__global__ void __launch_bounds__(256) k_xh(
    const void* __restrict__ h, const void* __restrict__ W,
    const void* __restrict__ att_src, const void* __restrict__ att_dst,
    const int* __restrict__ ei, bf16* __restrict__ x,
    float* __restrict__ a_src, float* __restrict__ a_dst,
    int* __restrict__ cnt, int N, int E) {
  __shared__ alignas(16) unsigned short hls[64 * 64];
  __shared__ alignas(16) unsigned short wls[256 * 64];
  bool f32 = det_f32((const unsigned*)h);
  bool i64 = det_i64(ei);
  if (f32) {
    if (i64) xh_body<true, true>(h, W, att_src, att_dst, ei, x, a_src, a_dst, cnt, N, E, hls, wls);
    else     xh_body<true, false>(h, W, att_src, att_dst, ei, x, a_src, a_dst, cnt, N, E, hls, wls);
  } else {
    if (i64) xh_body<false, true>(h, W, att_src, att_dst, ei, x, a_src, a_dst, cnt, N, E, hls, wls);
    else     xh_body<false, false>(h, W, att_src, att_dst, ei, x, a_src, a_dst, cnt, N, E, hls, wls);
  }
}

// ------------- scan phase 1: shuffle-based block scan + last-block bsum scan -
__global__ void __launch_bounds__(1024) k_bscan(
    const void* __restrict__ W_edge, const void* __restrict__ att_edge,
    const unsigned* __restrict__ hw, const int* __restrict__ cnt,
    int* __restrict__ offs, int* __restrict__ bsum, int* __restrict__ bbase,
    int* __restrict__ done, float* __restrict__ M, int N) {
  int b = blockIdx.x, t = threadIdx.x;
  int lane = t & 63, wvi = t >> 6;
  if (b == 0 && t < 768) {
    bool ff = det_f32(hw);
    int d = wvi >> 2, hh = wvi & 3;
    float p = ldr(W_edge, (size_t)d * 256 + hh * 64 + lane, ff) *
              ldr(att_edge, (size_t)hh * 64 + lane, ff);
#pragma unroll
    for (int o = 32; o; o >>= 1) p += __shfl_down(p, o);
    if (lane == 0) M[d * 4 + hh] = p;
  }
  const int C = (N + SCAN_G - 1) / SCAN_G;
  const int b0 = b * C;
  __shared__ int wsum[16];
  __shared__ int lastf;
  int v = (t < C && b0 + t < N) ? cnt[b0 + t] : 0;
  int inc = wave_iscan(v, lane);
  if (lane == 63) wsum[wvi] = inc;
  __syncthreads();
  if (wvi == 0) {
    int sv = (lane < 16) ? wsum[lane] : 0;
    sv = wave_iscan(sv, lane);
    if (lane < 16) wsum[lane] = sv;
  }
  __syncthreads();
  int base = wvi ? wsum[wvi - 1] : 0;
  int total = wsum[15];
  if (t < C && b0 + t < N) offs[b0 + t] = inc + base - v;  // exclusive prefix
  if (t == 0) {
    atomicExch(&bsum[b], total);
    __threadfence();
    int old = atomicAdd(done, 1);
    lastf = (old == SCAN_G - 1) ? 1 : 0;
  }
  __syncthreads();
  if (lastf) {  // this block saw all other totals published
    int v2 = (t < SCAN_G) ? atomicAdd(&bsum[t], 0) : 0;  // atomic read
    int inc2 = wave_iscan(v2, lane);
    __syncthreads();
    if (lane == 63) wsum[wvi] = inc2;
    __syncthreads();
    if (wvi == 0) {
      int sv = (lane < 16) ? wsum[lane] : 0;
      sv = wave_iscan(sv, lane);
      if (lane < 16) wsum[lane] = sv;
    }
    __syncthreads();
    int base2 = wvi ? wsum[wvi - 1] : 0;
    if (t < SCAN_G) bbase[t] = inc2 + base2 - v2;
  }
}

// ------------- scan phase 2: add block base, emit offs + cursor --------------
__global__ void __launch_bounds__(1024) k_add(
    int* __restrict__ offs, int* __restrict__ cursor,
    const int* __restrict__ bbase, int N, int E) {
  int b = blockIdx.x, t = threadIdx.x;
  const int C = (N + SCAN_G - 1) / SCAN_G;
  const int b0 = b * C;
  int base = bbase[b];
  if (t < C && b0 + t < N) {
    int o = offs[b0 + t] + base;
    offs[b0 + t] = o;
    cursor[b0 + t] = o;
  }
  if (b == 0 && t == 0) offs[N] = E;
}

// ---------------- fused edge weights + CSR scatter (one 16B slot) ------------
// 2 edges per thread (512-edge blocks) for doubled ILP on the latency chain.
template <bool FF, bool I64>
static __device__ __forceinline__ void es_one(
    const int* __restrict__ ei, const unsigned* __restrict__ sattr, int j,
    long long e, const float* __restrict__ a_src,
    const float* __restrict__ a_dst, const float4 m0, const float4 m1,
    const float4 m2, int* __restrict__ cursor, int4* __restrict__ slots,
    int E, int N) {
  if (e >= E) return;
  int src = clampN(ldi<I64>(ei, e), N);
  int dst = clampN(ldi<I64>(ei, (long long)E + e), N);
  float ea0, ea1, ea2;
  if (FF) {
    const float* sf = (const float*)sattr;
    ea0 = sf[j * 3 + 0];
    ea1 = sf[j * 3 + 1];
    ea2 = sf[j * 3 + 2];
  } else {
    const unsigned short* su = (const unsigned short*)sattr;
    ea0 = __uint_as_float((unsigned)su[j * 3 + 0] << 16);
    ea1 = __uint_as_float((unsigned)su[j * 3 + 1] << 16);
    ea2 = __uint_as_float((unsigned)su[j * 3 + 2] << 16);
  }
  const float4 as4 = ((const float4*)a_src)[src];
  const float4 ad4 = ((const float4*)a_dst)[dst];
  float al[4];
  al[0] = as4.x + ad4.x + ea0 * m0.x + ea1 * m1.x + ea2 * m2.x;
  al[1] = as4.y + ad4.y + ea0 * m0.y + ea1 * m1.y + ea2 * m2.y;
  al[2] = as4.z + ad4.z + ea0 * m0.z + ea1 * m1.z + ea2 * m2.z;
  al[3] = as4.w + ad4.w + ea0 * m0.w + ea1 * m1.w + ea2 * m2.w;
  unsigned short u[4];
#pragma unroll
  for (int hh = 0; hh < 4; hh++) {
    float a = al[hh];
    a = (a > 0.f) ? a : NEG_SLOPE * a;
    a = fminf(fmaxf(a, -60.f), 60.f);
    u[hh] = f2us(__expf(a));
  }
  int pos = atomicAdd(&cursor[dst], 1);
  slots[pos] = make_int4(src, (int)(u[0] | ((unsigned)u[1] << 16)),
                         (int)(u[2] | ((unsigned)u[3] << 16)), 0);
}

template <bool FF, bool I64>
static __device__ __forceinline__ void es_body(
    const int* __restrict__ ei, const void* __restrict__ eattr,
    const float* __restrict__ a_src, const float* __restrict__ a_dst,
    const float* __restrict__ M, int* __restrict__ cursor,
    int4* __restrict__ slots, int E, int N, unsigned* __restrict__ sattr) {
  const long long e0 = (long long)blockIdx.x * 512;
  {  // stage 512 edges' eattr: 6B/edge (bf16) or 12B/edge (f32)
    const unsigned bpe = FF ? 12u : 6u;
    const unsigned* gsrc = (const unsigned*)((const char*)eattr + e0 * bpe);
    unsigned ndw = FF ? 1536u : 768u;
    long long bytes_left = ((long long)E - e0) * bpe;
    if (bytes_left < 0) bytes_left = 0;
    unsigned max_dw = (unsigned)((bytes_left + 3) >> 2);
    if (ndw > max_dw) ndw = max_dw;
    for (unsigned i = threadIdx.x; i < ndw; i += 256) sattr[i] = gsrc[i];
  }
  __syncthreads();
  const float4 m0 = ((const float4*)M)[0];
  const float4 m1 = ((const float4*)M)[1];
  const float4 m2 = ((const float4*)M)[2];
  int t = threadIdx.x;
  es_one<FF, I64>(ei, sattr, t, e0 + t, a_src, a_dst, m0, m1, m2, cursor,
                  slots, E, N);
  es_one<FF, I64>(ei, sattr, t + 256, e0 + t + 256, a_src, a_dst, m0, m1, m2,
                  cursor, slots, E, N);
}

__global__ void __launch_bounds__(256) k_es(
    const int* __restrict__ ei, const void* __restrict__ eattr,
    const float* __restrict__ a_src, const float* __restrict__ a_dst,
    const float* __restrict__ M, const unsigned* __restrict__ hw,
    int* __restrict__ cursor, int4* __restrict__ slots, int E, int N) {
  __shared__ unsigned sattr[1536];
  bool f32 = det_f32(hw);
  bool i64 = det_i64(ei);
  if (f32) {
    if (i64) es_body<true, true>(ei, eattr, a_src, a_dst, M, cursor, slots, E, N, sattr);
    else     es_body<true, false>(ei, eattr, a_src, a_dst, M, cursor, slots, E, N, sattr);
  } else {
    if (i64) es_body<false, true>(ei, eattr, a_src, a_dst, M, cursor, slots, E, N, sattr);
    else     es_body<false, false>(ei, eattr, a_src, a_dst, M, cursor, slots, E, N, sattr);
  }
}

// ---------------- aggregation + head-mean + LayerNorm + SiLU -----------------
// Wave = node. Lane = 8B (uint2) of the 512B x-row => one gather per edge per
// node; slot int4 broadcast once. Head h = lane>>4, weight extracted with a
// per-lane precomputed shift. Epilogue fully in-register: head fold via
// shfl_xor(16,32), LN reduce via shfl_xor(1,2,4,8). No LDS, no barriers.
__global__ void __launch_bounds__(256) k_agg(
    const int* __restrict__ offs, const int4* __restrict__ slots,
    const uint2* __restrict__ xr, const unsigned* __restrict__ hw,
    const void* __restrict__ bias, const void* __restrict__ gamma,
    const void* __restrict__ beta, void* __restrict__ out, int N) {
  const int t = threadIdx.x;
  const int wv = t >> 6, lane = t & 63;
  const bool ff = det_f32(hw);
  const int n = blockIdx.x * 4 + wv;
  if (n >= N) return;
  const int h = lane >> 4;
  const int sh_w = (h & 1) ? 0 : 16;
  const bool hz = (h & 2) != 0;
  int s0 = offs[n], s1 = offs[n + 1];
  float a0 = 0.f, a1 = 0.f, a2 = 0.f, a3 = 0.f, ws = 0.f;
  int i = s0;
  for (; i + 4 <= s1; i += 4) {
    int4 q0 = slots[i], q1 = slots[i + 1], q2 = slots[i + 2], q3 = slots[i + 3];
    uint2 d0 = xr[(size_t)(unsigned)q0.x * 64 + lane];
    uint2 d1 = xr[(size_t)(unsigned)q1.x * 64 + lane];
    uint2 d2 = xr[(size_t)(unsigned)q2.x * 64 + lane];
    uint2 d3 = xr[(size_t)(unsigned)q3.x * 64 + lane];
    unsigned p0 = hz ? (unsigned)q0.z : (unsigned)q0.y;
    unsigned p1 = hz ? (unsigned)q1.z : (unsigned)q1.y;
    unsigned p2 = hz ? (unsigned)q2.z : (unsigned)q2.y;
    unsigned p3 = hz ? (unsigned)q3.z : (unsigned)q3.y;
    float w0 = __uint_as_float((p0 << sh_w) & 0xffff0000u);
    float w1 = __uint_as_float((p1 << sh_w) & 0xffff0000u);
    float w2 = __uint_as_float((p2 << sh_w) & 0xffff0000u);
    float w3 = __uint_as_float((p3 << sh_w) & 0xffff0000u);
    a0 += w0 * __uint_as_float(d0.x << 16);
    a1 += w0 * __uint_as_float(d0.x & 0xffff0000u);
    a2 += w0 * __uint_as_float(d0.y << 16);
    a3 += w0 * __uint_as_float(d0.y & 0xffff0000u);
    a0 += w1 * __uint_as_float(d1.x << 16);
    a1 += w1 * __uint_as_float(d1.x & 0xffff0000u);
    a2 += w1 * __uint_as_float(d1.y << 16);
    a3 += w1 * __uint_as_float(d1.y & 0xffff0000u);
    a0 += w2 * __uint_as_float(d2.x << 16);
    a1 += w2 * __uint_as_float(d2.x & 0xffff0000u);
    a2 += w2 * __uint_as_float(d2.y << 16);
    a3 += w2 * __uint_as_float(d2.y & 0xffff0000u);
    a0 += w3 * __uint_as_float(d3.x << 16);
    a1 += w3 * __uint_as_float(d3.x & 0xffff0000u);
    a2 += w3 * __uint_as_float(d3.y << 16);
    a3 += w3 * __uint_as_float(d3.y & 0xffff0000u);
    ws += (w0 + w1) + (w2 + w3);
  }
  for (; i < s1; i++) {
    int4 q = slots[i];
    uint2 d = xr[(size_t)(unsigned)q.x * 64 + lane];
    unsigned p = hz ? (unsigned)q.z : (unsigned)q.y;
    float w = __uint_as_float((p << sh_w) & 0xffff0000u);
    a0 += w * __uint_as_float(d.x << 16);
    a1 += w * __uint_as_float(d.x & 0xffff0000u);
    a2 += w * __uint_as_float(d.y << 16);
    a3 += w * __uint_as_float(d.y & 0xffff0000u);
    ws += w;
  }
  float inv = 1.f / (ws + 1e-16f);
  float m0 = a0 * inv, m1 = a1 * inv, m2 = a2 * inv, m3 = a3 * inv;
  // fold heads: lanes l, l^16, l^32, l^48 hold same channels, diff heads
  m0 += __shfl_xor(m0, 16); m0 += __shfl_xor(m0, 32);
  m1 += __shfl_xor(m1, 16); m1 += __shfl_xor(m1, 32);
  m2 += __shfl_xor(m2, 16); m2 += __shfl_xor(m2, 32);
  m3 += __shfl_xor(m3, 16); m3 += __shfl_xor(m3, 32);
  const int cb = (lane & 15) * 4;
  m0 = m0 * 0.25f + ldr(bias, cb + 0, ff);
  m1 = m1 * 0.25f + ldr(bias, cb + 1, ff);
  m2 = m2 * 0.25f + ldr(bias, cb + 2, ff);
  m3 = m3 * 0.25f + ldr(bias, cb + 3, ff);
  float s = (m0 + m1) + (m2 + m3);
#pragma unroll
  for (int mask = 1; mask < 16; mask <<= 1) s += __shfl_xor(s, mask);
  float mu = s * (1.f / 64.f);
  float d0 = m0 - mu, d1 = m1 - mu, d2 = m2 - mu, d3 = m3 - mu;
  float v = (d0 * d0 + d1 * d1) + (d2 * d2 + d3 * d3);
#pragma unroll
  for (int mask = 1; mask < 16; mask <<= 1) v += __shfl_xor(v, mask);
  float rs = rsqrtf(v * (1.f / 64.f) + 1e-5f);
  float y0 = d0 * rs * ldr(gamma, cb + 0, ff) + ldr(beta, cb + 0, ff);
  float y1 = d1 * rs * ldr(gamma, cb + 1, ff) + ldr(beta, cb + 1, ff);
  float y2 = d2 * rs * ldr(gamma, cb + 2, ff) + ldr(beta, cb + 2, ff);
  float y3 = d3 * rs * ldr(gamma, cb + 3, ff) + ldr(beta, cb + 3, ff);
  float r0 = y0 / (1.f + __expf(-y0));
  float r1 = y1 / (1.f + __expf(-y1));
  float r2 = y2 / (1.f + __expf(-y2));
  float r3 = y3 / (1.f + __expf(-y3));
  if (lane < 16) {
    if (ff) {
      float4 o = make_float4(r0, r1, r2, r3);
      ((float4*)out)[(size_t)n * 16 + lane] = o;
    } else {
      uint2 o;
      o.x = (unsigned)f2us(r0) | ((unsigned)f2us(r1) << 16);
      o.y = (unsigned)f2us(r2) | ((unsigned)f2us(r3) << 16);
      ((uint2*)out)[(size_t)n * 16 + lane] = o;
    }
  }
}

extern "C" void kernel_launch(void* const* d_in, const int* in_sizes, int n_in,
                              void* d_out, int out_size, void* d_ws,
                              size_t ws_size, hipStream_t stream) {
  const void* h        = d_in[1];
  const int*  ei       = (const int*)d_in[2];
  const void* eattr    = d_in[3];
  const void* W        = d_in[4];
  const void* att_src  = d_in[5];
  const void* att_dst  = d_in[6];
  const void* W_edge   = d_in[7];
  const void* att_edge = d_in[8];
  const void* bias     = d_in[9];
  const void* gamma    = d_in[10];
  const void* beta     = d_in[11];

  const int N = in_sizes[1] / HIDC;       // h has N*64 elements (any dtype)
  const int E = in_sizes[3] / 3;          // edge_attr has E*3 elements

  // Workspace layout (~40.7 MB), 16B-aligned segments.
  char* p = (char*)d_ws;
  float* M    = (float*)p; p += 64;                      // 12 floats
  bf16* x     = (bf16*)p;  p += (size_t)N * 256 * 2;     // 25.6 MB
  float* asrc = (float*)p; p += (size_t)N * 4 * 4;       // 0.8 MB
  float* adst = (float*)p; p += (size_t)N * 4 * 4;       // 0.8 MB
  int4* slots = (int4*)p;  p += (size_t)E * 16;          // 12.8 MB
  int* cnt    = (int*)p;   p += (size_t)N * 4;           // zeroed
  int* done   = (int*)p;   p += 64;                      // zeroed (with cnt)
  int* offs   = (int*)p;   p += ((size_t)N + 4) * 4;
  int* cursor = (int*)p;   p += (size_t)N * 4;
  int* bsum   = (int*)p;   p += SCAN_G * 4;
  int* bbase  = (int*)p;   p += SCAN_G * 4;

  size_t need = (size_t)(p - (char*)d_ws);
  if (ws_size < need || N <= 0 || E <= 0) {
    hipMemsetAsync(d_out, 0, (size_t)out_size * 2, stream);
    return;
  }

  hipMemsetAsync(cnt, 0, (size_t)N * 4 + 64, stream);  // cnt + done

  k_xh<<<(N + 63) / 64, 256, 0, stream>>>(h, W, att_src, att_dst, ei, x,
                                          asrc, adst, cnt, N, E);
  k_bscan<<<SCAN_G, 1024, 0, stream>>>(W_edge, att_edge, (const unsigned*)h,
                                       cnt, offs, bsum, bbase, done, M, N);
  k_add<<<SCAN_G, 1024, 0, stream>>>(offs, cursor, bbase, N, E);
  k_es<<<(E + 511) / 512, 256, 0, stream>>>(ei, eattr, asrc, adst, M,
                                            (const unsigned*)h, cursor, slots,
                                            E, N);
  k_agg<<<(N + 3) / 4, 256, 0, stream>>>(offs, slots, (const uint2*)x,
                                         (const unsigned*)h, bias, gamma, beta,
                                         d_out, N);
}